// Round 12
// baseline (70.077 us; speedup 1.0000x reference)
//
#include <hip/hip_runtime.h>
#include <math.h>

#define B 4
#define T 4096
#define H 2048
#define TT 256            // timesteps per tile (sab-barrier period)
#define NT (T / TT)       // 16 tiles
#define NBAND (H / 32)    // 64 bands of 32 channels
#define THREADS 1024      // 16 waves/CU
#define NSUB 32           // subchunks per tile
#define SUBL (TT / NSUB)  // 8 steps per subchunk

// ---------------------------------------------------------------------------
// Fused WKV, register-direct variant: block = (batch b, band of 32 channels),
// owns all T=4096 steps. k,v read ONCE, straight into registers (no LDS
// staging): thread (sub,ch) loads its 8 rows at [t][ch]; lanes 0-31 of a wave
// cover one full 128B line (ch 0..31), lanes 32-63 the row+8 line -> every
// HBM line fetched exactly once chip-wide. Next tile's 16 loads are issued at
// the top of each body and waited on by compiler-exact vmcnt at first use.
// Only ONE barrier per tile (sab publish); sab is double-buffered: tile j+1
// writes sab[(j+1)&1] while stragglers read sab[j&1]; tile j+2's overwrite of
// sab[j&1] is fenced by tile j+1's barrier. Manual 2x unroll keeps all
// register-array indices compile-time static (rule #20).
// ---------------------------------------------------------------------------
__global__ __launch_bounds__(THREADS)
void wkv_fused_kernel(const float* __restrict__ kg,
                      const float* __restrict__ vg,
                      const float* __restrict__ td,
                      const float* __restrict__ tf,
                      float* __restrict__ out) {
    __shared__ float2 sab[2][NSUB][32];   // double-buffered partials, 16KB

    int band = blockIdx.x & (NBAND - 1);
    int b    = blockIdx.x >> 6;           // / NBAND
    int tid  = threadIdx.x;
    int ch   = tid & 31;
    int sub  = tid >> 5;                  // 0..31

    const float* kbase = kg + (size_t)b * T * H + band * 32 + ch;
    const float* vbase = vg + (size_t)b * T * H + band * 32 + ch;
    float* obase       = out + (size_t)b * T * H + band * 32 + ch;

    int h = band * 32 + ch;
    float ew = expf(-expf(td[h]));
    float eu = expf(tf[h]);

    // powers of ew: ewL = ew^SUBL (=ew^8); ladder up to ew^256
    float e2 = ew * ew, e4 = e2 * e2;
    float ewL  = e4 * e4;                 // ew^8
    float l2   = ewL * ewL;               // ew^16
    float l4   = l2 * l2;                 // ew^32
    float l8   = l4 * l4;                 // ew^64
    float l16  = l8 * l8;                 // ew^128
    float ewT  = l16 * l16;               // ew^256 = ew^TT
    float ewpow = 1.0f;                   // ewL^sub
    if (sub & 1)  ewpow *= ewL;
    if (sub & 2)  ewpow *= l2;
    if (sub & 4)  ewpow *= l4;
    if (sub & 8)  ewpow *= l8;
    if (sub & 16) ewpow *= l16;

    float Ra = 0.f, Rb = 0.f;             // running state (redundant per thread)

    // row offset of step i of this thread's subchunk within tile j:
    //   ((size_t)j*TT + sub*SUBL + i) * H
    const size_t rbase = (size_t)sub * SUBL * H;

#define LOADTILE(J, KN, VN)                                                 \
    {                                                                       \
        _Pragma("unroll")                                                   \
        for (int i = 0; i < SUBL; ++i) {                                    \
            size_t off = (size_t)(J) * TT * H + rbase + (size_t)i * H;      \
            KN[i] = kbase[off];                                             \
            VN[i] = vbase[off];                                             \
        }                                                                   \
    }

#define TILE_BODY(J, KC, VC, KN, VN)                                        \
    {                                                                       \
        const int cur = (J) & 1;                                            \
        if ((J) + 1 < NT) LOADTILE((J) + 1, KN, VN);                        \
        /* Phase A: local scan of own 8-step subchunk (registers only) */   \
        float ek[SUBL], ekv[SUBL];                                          \
        float la = 0.f, lb = 0.f;                                           \
        _Pragma("unroll")                                                   \
        for (int i = 0; i < SUBL; ++i) {                                    \
            float e  = __expf(KC[i]);                                       \
            float ev = e * VC[i];                                           \
            ek[i]  = e;                                                     \
            ekv[i] = ev;                                                    \
            la = ew * la + ev;                                              \
            lb = ew * lb + e;                                               \
        }                                                                   \
        sab[cur][sub][ch] = make_float2(la, lb);                            \
        asm volatile("s_waitcnt lgkmcnt(0)" ::: "memory");                  \
        __builtin_amdgcn_s_barrier();    /* only barrier per tile */        \
        /* Phase B: scan 32 partials; capture exclusive prefix at s==sub */ \
        float ta = 0.f, tb = 0.f, pa = 0.f, pb = 0.f;                       \
        _Pragma("unroll")                                                   \
        for (int s = 0; s < NSUB; ++s) {                                    \
            float2 x = sab[cur][s][ch];                                     \
            bool cap = (s == sub);                                          \
            pa = cap ? ta : pa;                                             \
            pb = cap ? tb : pb;                                             \
            ta = ewL * ta + x.x;                                            \
            tb = ewL * tb + x.y;                                            \
        }                                                                   \
        float a2 = ewpow * Ra + pa;                                         \
        float b2 = ewpow * Rb + pb;                                         \
        Ra = ewT * Ra + ta;                                                 \
        Rb = ewT * Rb + tb;                                                 \
        /* Phase C: emit straight from registers */                         \
        _Pragma("unroll")                                                   \
        for (int i = 0; i < SUBL; ++i) {                                    \
            float num = a2 + eu * ekv[i];                                   \
            float den = b2 + eu * ek[i] + 1e-8f;                            \
            float inv;                                                      \
            asm("v_rcp_f32 %0, %1" : "=v"(inv) : "v"(den));                 \
            float r = num * inv;                                            \
            __builtin_nontemporal_store(                                    \
                r, obase + (size_t)(J) * TT * H + rbase + (size_t)i * H);   \
            a2 = ew * a2 + ekv[i];                                          \
            b2 = ew * b2 + ek[i];                                           \
        }                                                                   \
    }

    float ka[SUBL], va[SUBL], kb2[SUBL], vb2[SUBL];
    LOADTILE(0, ka, va);

    for (int j = 0; j < NT; j += 2) {     // NT=16 even; static reg indices
        TILE_BODY(j,     ka,  va,  kb2, vb2);
        TILE_BODY(j + 1, kb2, vb2, ka,  va);
    }

    // final states: outputs 1 (a) and 2 (b), each (B, H)
    if (tid < 32) {
        size_t so = (size_t)B * T * H;
        out[so + (size_t)b * H + h] = Ra;
        out[so + (size_t)B * H + (size_t)b * H + h] = Rb;
    }
}

extern "C" void kernel_launch(void* const* d_in, const int* in_sizes, int n_in,
                              void* d_out, int out_size, void* d_ws, size_t ws_size,
                              hipStream_t stream) {
    const float* k  = (const float*)d_in[0];
    const float* v  = (const float*)d_in[1];
    const float* td = (const float*)d_in[2];
    const float* tf = (const float*)d_in[3];
    float* out      = (float*)d_out;

    dim3 grid(B * NBAND);                 // 256 blocks = 1 per CU
    wkv_fused_kernel<<<grid, dim3(THREADS), 0, stream>>>(k, v, td, tf, out);
}

// Round 13
// 68.479 us; speedup vs baseline: 1.0233x; 1.0233x over previous
//
#include <hip/hip_runtime.h>
#include <math.h>

#define B 4
#define T 4096
#define H 2048
#define TT 512            // timesteps per tile (sab-barrier period)
#define NT (T / TT)       // 8 tiles
#define NBAND (H / 32)    // 64 bands of 32 channels
#define THREADS 1024      // 16 waves/CU
#define NSUB 32           // subchunks per tile
#define SUBL (TT / NSUB)  // 16 steps per subchunk

// ---------------------------------------------------------------------------
// Fused WKV, register-direct, TT=512: block = (batch b, band of 32 channels),
// owns all T=4096 steps. k,v read ONCE, straight into registers (no LDS
// staging): thread (sub,ch) loads its 16 rows at [t][ch]; lanes 0-31 of a
// wave cover one full 128B line, lanes 32-63 the next row's line -> every HBM
// line fetched exactly once chip-wide. Next tile's 32 loads are issued at the
// top of each body; compiler inserts dependency-exact vmcnt at first use.
// ONE barrier per tile (sab publish); sab double-buffered (tile j+1 writes
// sab[(j+1)&1] while stragglers read sab[j&1]; j+2's overwrite is fenced by
// j+1's barrier). Phase A overwrites k/v regs in place with ek/ekv to keep
// VGPR <= 128 (16 waves/CU). Manual 2x unroll -> all reg indices static.
// History: TT=256 register-direct = 70.1us; TT=128 LDS = 78us (per-tile
// overhead paid 2x as often); this tests the amortization direction.
// ---------------------------------------------------------------------------
__global__ __launch_bounds__(THREADS)
void wkv_fused_kernel(const float* __restrict__ kg,
                      const float* __restrict__ vg,
                      const float* __restrict__ td,
                      const float* __restrict__ tf,
                      float* __restrict__ out) {
    __shared__ float2 sab[2][NSUB][32];   // double-buffered partials, 16KB

    int band = blockIdx.x & (NBAND - 1);
    int b    = blockIdx.x >> 6;           // / NBAND
    int tid  = threadIdx.x;
    int ch   = tid & 31;
    int sub  = tid >> 5;                  // 0..31

    const float* kbase = kg + (size_t)b * T * H + band * 32 + ch;
    const float* vbase = vg + (size_t)b * T * H + band * 32 + ch;
    float* obase       = out + (size_t)b * T * H + band * 32 + ch;

    int h = band * 32 + ch;
    float ew = expf(-expf(td[h]));
    float eu = expf(tf[h]);

    // powers of ew: ewL = ew^SUBL (=ew^16); ladder up to ew^512 = ew^TT
    float e2 = ew * ew, e4 = e2 * e2, e8 = e4 * e4;
    float ewL  = e8 * e8;                 // ew^16
    float l2   = ewL * ewL;               // ew^32
    float l4   = l2 * l2;                 // ew^64
    float l8   = l4 * l4;                 // ew^128
    float l16  = l8 * l8;                 // ew^256
    float ewT  = l16 * l16;               // ew^512 = ew^TT
    float ewpow = 1.0f;                   // ewL^sub
    if (sub & 1)  ewpow *= ewL;
    if (sub & 2)  ewpow *= l2;
    if (sub & 4)  ewpow *= l4;
    if (sub & 8)  ewpow *= l8;
    if (sub & 16) ewpow *= l16;

    float Ra = 0.f, Rb = 0.f;             // running state (redundant per thread)

    // row offset of step i of this thread's subchunk within tile j:
    //   ((size_t)j*TT + sub*SUBL + i) * H
    const size_t rbase = (size_t)sub * SUBL * H;

#define LOADTILE(J, KN, VN)                                                 \
    {                                                                       \
        _Pragma("unroll")                                                   \
        for (int i = 0; i < SUBL; ++i) {                                    \
            size_t off = (size_t)(J) * TT * H + rbase + (size_t)i * H;      \
            KN[i] = kbase[off];                                             \
            VN[i] = vbase[off];                                             \
        }                                                                   \
    }

#define TILE_BODY(J, KC, VC, KN, VN)                                        \
    {                                                                       \
        const int cur = (J) & 1;                                            \
        if ((J) + 1 < NT) LOADTILE((J) + 1, KN, VN);                        \
        /* Phase A: local scan; overwrite KC/VC in place with ek/ekv */     \
        float la = 0.f, lb = 0.f;                                           \
        _Pragma("unroll")                                                   \
        for (int i = 0; i < SUBL; ++i) {                                    \
            float e  = __expf(KC[i]);                                       \
            float ev = e * VC[i];                                           \
            KC[i] = e;                                                      \
            VC[i] = ev;                                                     \
            la = ew * la + ev;                                              \
            lb = ew * lb + e;                                               \
        }                                                                   \
        sab[cur][sub][ch] = make_float2(la, lb);                            \
        asm volatile("s_waitcnt lgkmcnt(0)" ::: "memory");                  \
        __builtin_amdgcn_s_barrier();    /* only barrier per tile */        \
        /* Phase B: scan 32 partials; capture exclusive prefix at s==sub */ \
        float ta = 0.f, tb = 0.f, pa = 0.f, pb = 0.f;                       \
        _Pragma("unroll")                                                   \
        for (int s = 0; s < NSUB; ++s) {                                    \
            float2 x = sab[cur][s][ch];                                     \
            bool cap = (s == sub);                                          \
            pa = cap ? ta : pa;                                             \
            pb = cap ? tb : pb;                                             \
            ta = ewL * ta + x.x;                                            \
            tb = ewL * tb + x.y;                                            \
        }                                                                   \
        float a2 = ewpow * Ra + pa;                                         \
        float b2 = ewpow * Rb + pb;                                         \
        Ra = ewT * Ra + ta;                                                 \
        Rb = ewT * Rb + tb;                                                 \
        /* Phase C: emit straight from registers (ek/ekv in KC/VC) */       \
        _Pragma("unroll")                                                   \
        for (int i = 0; i < SUBL; ++i) {                                    \
            float num = a2 + eu * VC[i];                                    \
            float den = b2 + eu * KC[i] + 1e-8f;                            \
            float inv;                                                      \
            asm("v_rcp_f32 %0, %1" : "=v"(inv) : "v"(den));                 \
            float r = num * inv;                                            \
            __builtin_nontemporal_store(                                    \
                r, obase + (size_t)(J) * TT * H + rbase + (size_t)i * H);   \
            a2 = ew * a2 + VC[i];                                           \
            b2 = ew * b2 + KC[i];                                           \
        }                                                                   \
    }

    float ka[SUBL], va[SUBL], kb2[SUBL], vb2[SUBL];
    LOADTILE(0, ka, va);

    for (int j = 0; j < NT; j += 2) {     // NT=8 even; static reg indices
        TILE_BODY(j,     ka,  va,  kb2, vb2);
        TILE_BODY(j + 1, kb2, vb2, ka,  va);
    }

    // final states: outputs 1 (a) and 2 (b), each (B, H)
    if (tid < 32) {
        size_t so = (size_t)B * T * H;
        out[so + (size_t)b * H + h] = Ra;
        out[so + (size_t)B * H + (size_t)b * H + h] = Rb;
    }
}

extern "C" void kernel_launch(void* const* d_in, const int* in_sizes, int n_in,
                              void* d_out, int out_size, void* d_ws, size_t ws_size,
                              hipStream_t stream) {
    const float* k  = (const float*)d_in[0];
    const float* v  = (const float*)d_in[1];
    const float* td = (const float*)d_in[2];
    const float* tf = (const float*)d_in[3];
    float* out      = (float*)d_out;

    dim3 grid(B * NBAND);                 // 256 blocks = 1 per CU
    wkv_fused_kernel<<<grid, dim3(THREADS), 0, stream>>>(k, v, td, tf, out);
}